// Round 1
// baseline (2559.219 us; speedup 1.0000x reference)
//
#include <hip/hip_runtime.h>
#include <math.h>

#define NN 50000
#define NE 800000
// D = 128, H = 256

// ---------------- degree / norm prep ----------------

__global__ __launch_bounds__(256) void k_deg(const int* __restrict__ ei,
                                             const int* __restrict__ nei,
                                             const float* __restrict__ w,
                                             float* __restrict__ deg1,
                                             float* __restrict__ deg2) {
  int e = blockIdx.x * 256 + threadIdx.x;
  if (e < NE) {
    atomicAdd(&deg1[ei[NE + e]], w[e]);
    atomicAdd(&deg2[nei[NE + e]], 1.0f);
  }
}

__global__ __launch_bounds__(256) void k_dinv(float* __restrict__ d, int n) {
  int i = blockIdx.x * 256 + threadIdx.x;
  if (i < n) {
    float v = d[i];
    d[i] = v > 0.0f ? (1.0f / sqrtf(v)) : 0.0f;
  }
}

__global__ __launch_bounds__(256) void k_norm(const int* __restrict__ ei,
                                              const int* __restrict__ nei,
                                              const float* __restrict__ w,
                                              const float* __restrict__ dinv1,
                                              const float* __restrict__ dinv2,
                                              float* __restrict__ norm1,
                                              float* __restrict__ norm2) {
  int e = blockIdx.x * 256 + threadIdx.x;
  if (e < NE) {
    norm1[e] = dinv1[ei[e]] * w[e] * dinv1[ei[NE + e]];
    norm2[e] = dinv2[nei[e]] * dinv2[nei[NE + e]];
  }
}

// ---------------- GEMM1: h1[N,256] = emb[ids] @ W_in[128,256] ----------------
// 32-row tile, 256 thr, thread tile 4 rows x 8 cols.

__global__ __launch_bounds__(256) void k_gemm_in(const float* __restrict__ emb,
                                                 const int* __restrict__ ids,
                                                 const float* __restrict__ W,
                                                 float* __restrict__ C) {
  __shared__ float As[32][128];
  int r0 = blockIdx.x * 32;
  int t = threadIdx.x;
  for (int i = t; i < 1024; i += 256) {
    int r = i >> 5, q = (i & 31) << 2;
    int rr = r0 + r;
    float4 v = make_float4(0.f, 0.f, 0.f, 0.f);
    if (rr < NN) v = *(const float4*)(emb + (size_t)ids[rr] * 128 + q);
    *(float4*)(&As[r][q]) = v;
  }
  __syncthreads();
  int tc = t & 31, tr = t >> 5;
  int c0 = tc * 8, rr0 = tr * 4;
  float acc[4][8];
#pragma unroll
  for (int r = 0; r < 4; r++)
#pragma unroll
    for (int c = 0; c < 8; c++) acc[r][c] = 0.f;

  for (int k0 = 0; k0 < 128; k0 += 4) {
    float a_[4][4];
#pragma unroll
    for (int r = 0; r < 4; r++) {
      float4 v = *(const float4*)(&As[rr0 + r][k0]);
      a_[r][0] = v.x; a_[r][1] = v.y; a_[r][2] = v.z; a_[r][3] = v.w;
    }
#pragma unroll
    for (int kk = 0; kk < 4; kk++) {
      float4 w0 = *(const float4*)(W + (size_t)(k0 + kk) * 256 + c0);
      float4 w1 = *(const float4*)(W + (size_t)(k0 + kk) * 256 + c0 + 4);
#pragma unroll
      for (int r = 0; r < 4; r++) {
        float av = a_[r][kk];
        acc[r][0] += av * w0.x; acc[r][1] += av * w0.y;
        acc[r][2] += av * w0.z; acc[r][3] += av * w0.w;
        acc[r][4] += av * w1.x; acc[r][5] += av * w1.y;
        acc[r][6] += av * w1.z; acc[r][7] += av * w1.w;
      }
    }
  }
#pragma unroll
  for (int r = 0; r < 4; r++) {
    int rr = r0 + rr0 + r;
    if (rr < NN) {
      float4 o0 = make_float4(acc[r][0], acc[r][1], acc[r][2], acc[r][3]);
      float4 o1 = make_float4(acc[r][4], acc[r][5], acc[r][6], acc[r][7]);
      *(float4*)(C + (size_t)rr * 256 + c0) = o0;
      *(float4*)(C + (size_t)rr * 256 + c0 + 4) = o1;
    }
  }
}

// ---------------- GEMM2: h2[N,128] = x1[N,256] @ W_out[256,128] ----------------

__global__ __launch_bounds__(256) void k_gemm_mid(const float* __restrict__ X,
                                                  const float* __restrict__ W,
                                                  float* __restrict__ C) {
  __shared__ float As[32][256];
  int r0 = blockIdx.x * 32;
  int t = threadIdx.x;
  for (int i = t; i < 2048; i += 256) {
    int r = i >> 6, q = (i & 63) << 2;
    int rr = r0 + r;
    float4 v = make_float4(0.f, 0.f, 0.f, 0.f);
    if (rr < NN) v = *(const float4*)(X + (size_t)rr * 256 + q);
    *(float4*)(&As[r][q]) = v;
  }
  __syncthreads();
  int tc = t & 31, tr = t >> 5;
  int c0 = tc * 4, rr0 = tr * 4;
  float acc[4][4];
#pragma unroll
  for (int r = 0; r < 4; r++)
#pragma unroll
    for (int c = 0; c < 4; c++) acc[r][c] = 0.f;

  for (int k0 = 0; k0 < 256; k0 += 4) {
    float a_[4][4];
#pragma unroll
    for (int r = 0; r < 4; r++) {
      float4 v = *(const float4*)(&As[rr0 + r][k0]);
      a_[r][0] = v.x; a_[r][1] = v.y; a_[r][2] = v.z; a_[r][3] = v.w;
    }
#pragma unroll
    for (int kk = 0; kk < 4; kk++) {
      float4 w = *(const float4*)(W + (size_t)(k0 + kk) * 128 + c0);
#pragma unroll
      for (int r = 0; r < 4; r++) {
        float av = a_[r][kk];
        acc[r][0] += av * w.x; acc[r][1] += av * w.y;
        acc[r][2] += av * w.z; acc[r][3] += av * w.w;
      }
    }
  }
#pragma unroll
  for (int r = 0; r < 4; r++) {
    int rr = r0 + rr0 + r;
    if (rr < NN) {
      float4 o = make_float4(acc[r][0], acc[r][1], acc[r][2], acc[r][3]);
      *(float4*)(C + (size_t)rr * 128 + c0) = o;
    }
  }
}

// ---------------- scatters (edge aggregation, fp32 atomics) ----------------

__global__ __launch_bounds__(256) void k_scatter1(const float* __restrict__ h,
                                                  const int* __restrict__ ei,
                                                  const float* __restrict__ norm,
                                                  float* __restrict__ agg) {
  int t = threadIdx.x;
  int ebase = blockIdx.x * 8;
#pragma unroll
  for (int j = 0; j < 8; j++) {
    int e = ebase + j;
    float nv = norm[e];
    if (nv != 0.f) {
      int r = ei[e], c = ei[NE + e];
      float val = h[(size_t)r * 256 + t] * nv;
      atomicAdd(agg + (size_t)c * 256 + t, val);
    }
  }
}

__global__ __launch_bounds__(256) void k_scatter2(const float* __restrict__ h,
                                                  const int* __restrict__ nei,
                                                  const float* __restrict__ norm,
                                                  float* __restrict__ agg) {
  int t = threadIdx.x;
  int half = t >> 7, d = t & 127;
  int ebase = blockIdx.x * 16;
#pragma unroll
  for (int j = 0; j < 8; j++) {
    int e = ebase + j * 2 + half;
    float nv = norm[e];
    if (nv != 0.f) {
      int r = nei[e], c = nei[NE + e];
      float val = h[(size_t)r * 128 + d] * nv;
      atomicAdd(agg + (size_t)c * 128 + d, val);
    }
  }
}

// ---------------- bias + ELU (in place) ----------------

__global__ __launch_bounds__(256) void k_bias_elu(float* __restrict__ X,
                                                  const float* __restrict__ b,
                                                  int dmask) {
  int i = blockIdx.x * 256 + threadIdx.x;
  float v = X[i] + b[i & dmask];
  X[i] = v > 0.f ? v : expm1f(v);
}

// ---------------- fused edge decoder ----------------
// block = 32 edges, 256 threads. LDS: concat feats 32x256 + t1 32x128.

__global__ __launch_bounds__(256) void k_decoder(const float* __restrict__ x2,
                                                 const int* __restrict__ ei,
                                                 const float* __restrict__ W1,
                                                 const float* __restrict__ b1,
                                                 const float* __restrict__ W2,
                                                 const float* __restrict__ b2,
                                                 const float* __restrict__ W3,
                                                 const float* __restrict__ b3,
                                                 float* __restrict__ out) {
  __shared__ float As[32][256];
  __shared__ float T[32][128];
  __shared__ int s_src[32], s_dst[32];
  int e0 = blockIdx.x * 32;
  int t = threadIdx.x;
  if (t < 32) s_src[t] = ei[e0 + t];
  else if (t < 64) s_dst[t - 32] = ei[NE + e0 + (t - 32)];
  __syncthreads();
  // load concat([x2[src], x2[dst]]) rows
  for (int i = t; i < 2048; i += 256) {
    int le = i >> 6, q = i & 63;
    int node = (q < 32) ? s_src[le] : s_dst[le];
    int qq = (q & 31) << 2;
    *(float4*)(&As[le][q << 2]) = *(const float4*)(x2 + (size_t)node * 128 + qq);
  }
  __syncthreads();

  int tc = t & 31, tr = t >> 5;
  int c0 = tc * 4, r0 = tr * 4;

  // layer 1: [32,256] @ W1[256,128], relu -> T
  float acc[4][4];
#pragma unroll
  for (int r = 0; r < 4; r++)
#pragma unroll
    for (int c = 0; c < 4; c++) acc[r][c] = 0.f;
  for (int k0 = 0; k0 < 256; k0 += 4) {
    float a_[4][4];
#pragma unroll
    for (int r = 0; r < 4; r++) {
      float4 v = *(const float4*)(&As[r0 + r][k0]);
      a_[r][0] = v.x; a_[r][1] = v.y; a_[r][2] = v.z; a_[r][3] = v.w;
    }
#pragma unroll
    for (int kk = 0; kk < 4; kk++) {
      float4 w = *(const float4*)(W1 + (size_t)(k0 + kk) * 128 + c0);
#pragma unroll
      for (int r = 0; r < 4; r++) {
        float av = a_[r][kk];
        acc[r][0] += av * w.x; acc[r][1] += av * w.y;
        acc[r][2] += av * w.z; acc[r][3] += av * w.w;
      }
    }
  }
  {
    float4 bb = *(const float4*)(b1 + c0);
#pragma unroll
    for (int r = 0; r < 4; r++) {
      float4 o;
      o.x = fmaxf(acc[r][0] + bb.x, 0.f);
      o.y = fmaxf(acc[r][1] + bb.y, 0.f);
      o.z = fmaxf(acc[r][2] + bb.z, 0.f);
      o.w = fmaxf(acc[r][3] + bb.w, 0.f);
      *(float4*)(&T[r0 + r][c0]) = o;
    }
  }
  __syncthreads();

  // layer 2: [32,128] @ W2[128,128], relu -> As[:, 0:128]
  float acc2[4][4];
#pragma unroll
  for (int r = 0; r < 4; r++)
#pragma unroll
    for (int c = 0; c < 4; c++) acc2[r][c] = 0.f;
  for (int k0 = 0; k0 < 128; k0 += 4) {
    float a_[4][4];
#pragma unroll
    for (int r = 0; r < 4; r++) {
      float4 v = *(const float4*)(&T[r0 + r][k0]);
      a_[r][0] = v.x; a_[r][1] = v.y; a_[r][2] = v.z; a_[r][3] = v.w;
    }
#pragma unroll
    for (int kk = 0; kk < 4; kk++) {
      float4 w = *(const float4*)(W2 + (size_t)(k0 + kk) * 128 + c0);
#pragma unroll
      for (int r = 0; r < 4; r++) {
        float av = a_[r][kk];
        acc2[r][0] += av * w.x; acc2[r][1] += av * w.y;
        acc2[r][2] += av * w.z; acc2[r][3] += av * w.w;
      }
    }
  }
  __syncthreads();   // all As reads done (layer1), safe to overwrite
  {
    float4 bb = *(const float4*)(b2 + c0);
#pragma unroll
    for (int r = 0; r < 4; r++) {
      float4 o;
      o.x = fmaxf(acc2[r][0] + bb.x, 0.f);
      o.y = fmaxf(acc2[r][1] + bb.y, 0.f);
      o.z = fmaxf(acc2[r][2] + bb.z, 0.f);
      o.w = fmaxf(acc2[r][3] + bb.w, 0.f);
      *(float4*)(&As[r0 + r][c0]) = o;
    }
  }
  __syncthreads();

  // layer 3: dot(t2, W3) + b3
  int le = t >> 3, j0 = (t & 7) * 16;
  float s = 0.f;
#pragma unroll
  for (int j = 0; j < 16; j += 4) {
    float4 v = *(const float4*)(&As[le][j0 + j]);
    float4 w = *(const float4*)(W3 + j0 + j);
    s += v.x * w.x + v.y * w.y + v.z * w.z + v.w * w.w;
  }
  s += __shfl_down(s, 4);
  s += __shfl_down(s, 2);
  s += __shfl_down(s, 1);
  if ((t & 7) == 0) out[e0 + le] = s + b3[0];
}

// ---------------- launch ----------------

extern "C" void kernel_launch(void* const* d_in, const int* in_sizes, int n_in,
                              void* d_out, int out_size, void* d_ws, size_t ws_size,
                              hipStream_t stream) {
  const int*   node_ids = (const int*)d_in[0];
  const int*   ei       = (const int*)d_in[1];
  const int*   nei      = (const int*)d_in[2];
  const float* eattr    = (const float*)d_in[3];
  const float* emb      = (const float*)d_in[4];
  const float* W_in     = (const float*)d_in[5];
  const float* b_in     = (const float*)d_in[6];
  const float* W_out    = (const float*)d_in[7];
  const float* b_out    = (const float*)d_in[8];
  const float* W1       = (const float*)d_in[9];
  const float* b1       = (const float*)d_in[10];
  const float* W2       = (const float*)d_in[11];
  const float* b2       = (const float*)d_in[12];
  const float* W3       = (const float*)d_in[13];
  const float* b3       = (const float*)d_in[14];
  float* out = (float*)d_out;

  // workspace layout (floats): bufA[N*256] | bufB[N*256] | norm1[E] | norm2[E]
  //                            | dinv1[N] | dinv2[N]   -> ~109.5 MB total
  float* ws    = (float*)d_ws;
  float* bufA  = ws;
  float* bufB  = bufA + (size_t)NN * 256;
  float* norm1 = bufB + (size_t)NN * 256;
  float* norm2 = norm1 + NE;
  float* dinv1 = norm2 + NE;
  float* dinv2 = dinv1 + NN;

  // degrees -> dinv
  hipMemsetAsync(dinv1, 0, 2 * (size_t)NN * sizeof(float), stream);
  k_deg<<<NE / 256, 256, 0, stream>>>(ei, nei, eattr, dinv1, dinv2);
  k_dinv<<<(2 * NN + 255) / 256, 256, 0, stream>>>(dinv1, 2 * NN);
  k_norm<<<NE / 256, 256, 0, stream>>>(ei, nei, eattr, dinv1, dinv2, norm1, norm2);

  // layer 1: h1 = emb[ids] @ W_in ; agg ; elu
  k_gemm_in<<<(NN + 31) / 32, 256, 0, stream>>>(emb, node_ids, W_in, bufA);
  hipMemsetAsync(bufB, 0, (size_t)NN * 256 * sizeof(float), stream);
  k_scatter1<<<NE / 8, 256, 0, stream>>>(bufA, ei, norm1, bufB);
  k_bias_elu<<<NN, 256, 0, stream>>>(bufB, b_in, 255);   // NN*256/256 = NN blocks

  // layer 2: h2 = x1 @ W_out ; agg ; elu
  k_gemm_mid<<<(NN + 31) / 32, 256, 0, stream>>>(bufB, W_out, bufA);
  hipMemsetAsync(bufB, 0, (size_t)NN * 128 * sizeof(float), stream);
  k_scatter2<<<NE / 16, 256, 0, stream>>>(bufA, nei, norm2, bufB);
  k_bias_elu<<<NN / 2, 256, 0, stream>>>(bufB, b_out, 127); // NN*128/256

  // decoder
  k_decoder<<<NE / 32, 256, 0, stream>>>(bufB, ei, W1, b1, W2, b2, W3, b3, out);
}

// Round 2
// 1984.906 us; speedup vs baseline: 1.2893x; 1.2893x over previous
//
#include <hip/hip_runtime.h>
#include <math.h>

#define NN 50000
#define NE 800000
// D = 128, H = 256

typedef __attribute__((ext_vector_type(8))) short s8_t;   // 8 bf16
typedef __attribute__((ext_vector_type(4))) float f4_t;   // 4 fp32

__device__ __forceinline__ short bf16_rne(float v) {
  unsigned u = __float_as_uint(v);
  unsigned r = (u + 0x7FFFu + ((u >> 16) & 1u)) >> 16;
  return (short)r;
}
__device__ __forceinline__ float bf16_tof(short h) {
  return __uint_as_float(((unsigned)(unsigned short)h) << 16);
}
__device__ __forceinline__ void split2(float v, short& hi, short& lo) {
  hi = bf16_rne(v);
  lo = bf16_rne(v - bf16_tof(hi));
}

// ---------------- degree / norm prep ----------------

__global__ __launch_bounds__(256) void k_deg(const int* __restrict__ ei,
                                             const int* __restrict__ nei,
                                             const float* __restrict__ w,
                                             float* __restrict__ deg1,
                                             float* __restrict__ deg2) {
  int e = blockIdx.x * 256 + threadIdx.x;
  if (e < NE) {
    atomicAdd(&deg1[ei[NE + e]], w[e]);
    atomicAdd(&deg2[nei[NE + e]], 1.0f);
  }
}

__global__ __launch_bounds__(256) void k_dinv(float* __restrict__ d, int n) {
  int i = blockIdx.x * 256 + threadIdx.x;
  if (i < n) {
    float v = d[i];
    d[i] = v > 0.0f ? (1.0f / sqrtf(v)) : 0.0f;
  }
}

__global__ __launch_bounds__(256) void k_norm(const int* __restrict__ ei,
                                              const int* __restrict__ nei,
                                              const float* __restrict__ w,
                                              const float* __restrict__ dinv1,
                                              const float* __restrict__ dinv2,
                                              float* __restrict__ norm1,
                                              float* __restrict__ norm2) {
  int e = blockIdx.x * 256 + threadIdx.x;
  if (e < NE) {
    norm1[e] = dinv1[ei[e]] * w[e] * dinv1[ei[NE + e]];
    norm2[e] = dinv2[nei[e]] * dinv2[nei[NE + e]];
  }
}

// ---------------- weight split/transpose for decoder MFMA ----------------
// W1[256][128] -> W1T_hi/lo[128][256] bf16 ; W2[128][128] -> W2T_hi/lo[128][128]

__global__ __launch_bounds__(256) void k_wcvt(const float* __restrict__ W1,
                                              const float* __restrict__ W2,
                                              short* __restrict__ w1th,
                                              short* __restrict__ w1tl,
                                              short* __restrict__ w2th,
                                              short* __restrict__ w2tl) {
  int i = blockIdx.x * 256 + threadIdx.x;
  if (i < 32768) {
    int k = i >> 7, n = i & 127;
    short h, l; split2(W1[i], h, l);
    w1th[n * 256 + k] = h; w1tl[n * 256 + k] = l;
  } else if (i < 49152) {
    int j = i - 32768;
    int k = j >> 7, n = j & 127;
    short h, l; split2(W2[j], h, l);
    w2th[n * 128 + k] = h; w2tl[n * 128 + k] = l;
  }
}

// ---------------- GEMM1: h1[N,256] = emb[ids] @ W_in[128,256] ----------------

__global__ __launch_bounds__(256) void k_gemm_in(const float* __restrict__ emb,
                                                 const int* __restrict__ ids,
                                                 const float* __restrict__ W,
                                                 float* __restrict__ C) {
  __shared__ float As[32][128];
  int r0 = blockIdx.x * 32;
  int t = threadIdx.x;
  for (int i = t; i < 1024; i += 256) {
    int r = i >> 5, q = (i & 31) << 2;
    int rr = r0 + r;
    float4 v = make_float4(0.f, 0.f, 0.f, 0.f);
    if (rr < NN) v = *(const float4*)(emb + (size_t)ids[rr] * 128 + q);
    *(float4*)(&As[r][q]) = v;
  }
  __syncthreads();
  int tc = t & 31, tr = t >> 5;
  int c0 = tc * 8, rr0 = tr * 4;
  float acc[4][8];
#pragma unroll
  for (int r = 0; r < 4; r++)
#pragma unroll
    for (int c = 0; c < 8; c++) acc[r][c] = 0.f;

  for (int k0 = 0; k0 < 128; k0 += 4) {
    float a_[4][4];
#pragma unroll
    for (int r = 0; r < 4; r++) {
      float4 v = *(const float4*)(&As[rr0 + r][k0]);
      a_[r][0] = v.x; a_[r][1] = v.y; a_[r][2] = v.z; a_[r][3] = v.w;
    }
#pragma unroll
    for (int kk = 0; kk < 4; kk++) {
      float4 w0 = *(const float4*)(W + (size_t)(k0 + kk) * 256 + c0);
      float4 w1 = *(const float4*)(W + (size_t)(k0 + kk) * 256 + c0 + 4);
#pragma unroll
      for (int r = 0; r < 4; r++) {
        float av = a_[r][kk];
        acc[r][0] += av * w0.x; acc[r][1] += av * w0.y;
        acc[r][2] += av * w0.z; acc[r][3] += av * w0.w;
        acc[r][4] += av * w1.x; acc[r][5] += av * w1.y;
        acc[r][6] += av * w1.z; acc[r][7] += av * w1.w;
      }
    }
  }
#pragma unroll
  for (int r = 0; r < 4; r++) {
    int rr = r0 + rr0 + r;
    if (rr < NN) {
      float4 o0 = make_float4(acc[r][0], acc[r][1], acc[r][2], acc[r][3]);
      float4 o1 = make_float4(acc[r][4], acc[r][5], acc[r][6], acc[r][7]);
      *(float4*)(C + (size_t)rr * 256 + c0) = o0;
      *(float4*)(C + (size_t)rr * 256 + c0 + 4) = o1;
    }
  }
}

// ---------------- GEMM2: h2[N,128] = x1[N,256] @ W_out[256,128] ----------------

__global__ __launch_bounds__(256) void k_gemm_mid(const float* __restrict__ X,
                                                  const float* __restrict__ W,
                                                  float* __restrict__ C) {
  __shared__ float As[32][256];
  int r0 = blockIdx.x * 32;
  int t = threadIdx.x;
  for (int i = t; i < 2048; i += 256) {
    int r = i >> 6, q = (i & 63) << 2;
    int rr = r0 + r;
    float4 v = make_float4(0.f, 0.f, 0.f, 0.f);
    if (rr < NN) v = *(const float4*)(X + (size_t)rr * 256 + q);
    *(float4*)(&As[r][q]) = v;
  }
  __syncthreads();
  int tc = t & 31, tr = t >> 5;
  int c0 = tc * 4, rr0 = tr * 4;
  float acc[4][4];
#pragma unroll
  for (int r = 0; r < 4; r++)
#pragma unroll
    for (int c = 0; c < 4; c++) acc[r][c] = 0.f;

  for (int k0 = 0; k0 < 256; k0 += 4) {
    float a_[4][4];
#pragma unroll
    for (int r = 0; r < 4; r++) {
      float4 v = *(const float4*)(&As[rr0 + r][k0]);
      a_[r][0] = v.x; a_[r][1] = v.y; a_[r][2] = v.z; a_[r][3] = v.w;
    }
#pragma unroll
    for (int kk = 0; kk < 4; kk++) {
      float4 w = *(const float4*)(W + (size_t)(k0 + kk) * 128 + c0);
#pragma unroll
      for (int r = 0; r < 4; r++) {
        float av = a_[r][kk];
        acc[r][0] += av * w.x; acc[r][1] += av * w.y;
        acc[r][2] += av * w.z; acc[r][3] += av * w.w;
      }
    }
  }
#pragma unroll
  for (int r = 0; r < 4; r++) {
    int rr = r0 + rr0 + r;
    if (rr < NN) {
      float4 o = make_float4(acc[r][0], acc[r][1], acc[r][2], acc[r][3]);
      *(float4*)(C + (size_t)rr * 128 + c0) = o;
    }
  }
}

// ---------------- scatters (edge aggregation, fp32 atomics) ----------------

__global__ __launch_bounds__(256) void k_scatter1(const float* __restrict__ h,
                                                  const int* __restrict__ ei,
                                                  const float* __restrict__ norm,
                                                  float* __restrict__ agg) {
  int t = threadIdx.x;
  int ebase = blockIdx.x * 8;
#pragma unroll
  for (int j = 0; j < 8; j++) {
    int e = ebase + j;
    float nv = norm[e];
    if (nv != 0.f) {
      int r = ei[e], c = ei[NE + e];
      float val = h[(size_t)r * 256 + t] * nv;
      atomicAdd(agg + (size_t)c * 256 + t, val);
    }
  }
}

__global__ __launch_bounds__(256) void k_scatter2(const float* __restrict__ h,
                                                  const int* __restrict__ nei,
                                                  const float* __restrict__ norm,
                                                  float* __restrict__ agg) {
  int t = threadIdx.x;
  int half = t >> 7, d = t & 127;
  int ebase = blockIdx.x * 16;
#pragma unroll
  for (int j = 0; j < 8; j++) {
    int e = ebase + j * 2 + half;
    float nv = norm[e];
    if (nv != 0.f) {
      int r = nei[e], c = nei[NE + e];
      float val = h[(size_t)r * 128 + d] * nv;
      atomicAdd(agg + (size_t)c * 128 + d, val);
    }
  }
}

// ---------------- bias + ELU (in place, layer1) ----------------

__global__ __launch_bounds__(256) void k_bias_elu(float* __restrict__ X,
                                                  const float* __restrict__ b,
                                                  int dmask) {
  int i = blockIdx.x * 256 + threadIdx.x;
  float v = X[i] + b[i & dmask];
  X[i] = v > 0.f ? v : expm1f(v);
}

// ---------------- bias + ELU + bf16 hi/lo split (layer2 output -> decoder input) ----

__global__ __launch_bounds__(256) void k_x2cvt(const float* __restrict__ X,
                                               const float* __restrict__ b,
                                               short* __restrict__ xh,
                                               short* __restrict__ xl) {
  int i = blockIdx.x * 256 + threadIdx.x;
  float v = X[i] + b[i & 127];
  v = v > 0.f ? v : expm1f(v);
  short h, l; split2(v, h, l);
  xh[i] = h; xl[i] = l;
}

// ---------------- fused edge decoder, split-bf16 MFMA ----------------
// block = 32 edges, 256 threads (4 waves). Wave w owns output cols [w*32, w*32+32).
// LDS strides padded (264 / 136 / 132) to break row-bank aliasing.

#define SA 264   // concat-feature LDS stride (256 cols + pad)
#define ST 136   // layer-1 output stride (128 + pad)
#define S2 132   // layer-2 output fp32 stride (128 + pad)

__global__ __launch_bounds__(256, 3) void k_decoder(
    const short* __restrict__ xh, const short* __restrict__ xl,
    const int* __restrict__ ei,
    const short* __restrict__ w1th, const short* __restrict__ w1tl,
    const float* __restrict__ b1,
    const short* __restrict__ w2th, const short* __restrict__ w2tl,
    const float* __restrict__ b2,
    const float* __restrict__ W3, const float* __restrict__ b3,
    float* __restrict__ out) {
  __shared__ short Ah[32 * SA];            // 16.9 KB
  __shared__ short Al[32 * SA];            // 16.9 KB
  __shared__ short Th[32 * ST];            // 8.7 KB
  __shared__ short Tl[32 * ST];            // 8.7 KB
  float* T2 = (float*)Ah;                  // 32*S2*4 = 16.9 KB, aliases Ah (dead after layer1)
  __shared__ int s_src[32], s_dst[32];

  int e0 = blockIdx.x * 32;
  int t = threadIdx.x;
  if (t < 32) s_src[t] = ei[e0 + t];
  else if (t < 64) s_dst[t - 32] = ei[NE + e0 + (t - 32)];
  __syncthreads();

  // gather concat([x2[src], x2[dst]]) hi/lo bf16 rows into LDS
  for (int i = t; i < 2048; i += 256) {
    int arr = i >> 10;                 // 0 = hi, 1 = lo
    int rem = i & 1023;
    int le = rem >> 5, q = rem & 31;   // q: 16B chunk within 256-col row
    int node = (q < 16) ? s_src[le] : s_dst[le];
    const short* src = (arr ? xl : xh) + (size_t)node * 128 + (q & 15) * 8;
    short* dst = (arr ? Al : Ah) + le * SA + q * 8;
    *(uint4*)dst = *(const uint4*)src;
  }
  __syncthreads();

  int w = t >> 6, lane = t & 63;
  int quad = lane >> 4, l16 = lane & 15;
  int nb = w * 32;

  int aoff0 = (0 + l16) * SA + quad * 8;
  int aoff1 = (16 + l16) * SA + quad * 8;
  int boff0 = (nb + l16) * 256 + quad * 8;
  int boff1 = (nb + 16 + l16) * 256 + quad * 8;

  // ---- layer 1: [32,256] @ W1[256,128] (hi*hi + hi*lo + lo*hi) ----
  f4_t acc[2][2];
#pragma unroll
  for (int mi = 0; mi < 2; mi++)
#pragma unroll
    for (int ni = 0; ni < 2; ni++) acc[mi][ni] = (f4_t){0.f, 0.f, 0.f, 0.f};

#pragma unroll
  for (int k0 = 0; k0 < 256; k0 += 32) {
    s8_t ah0 = *(const s8_t*)&Ah[aoff0 + k0];
    s8_t ah1 = *(const s8_t*)&Ah[aoff1 + k0];
    s8_t al0 = *(const s8_t*)&Al[aoff0 + k0];
    s8_t al1 = *(const s8_t*)&Al[aoff1 + k0];
    s8_t bh0 = *(const s8_t*)(w1th + boff0 + k0);
    s8_t bh1 = *(const s8_t*)(w1th + boff1 + k0);
    s8_t bl0 = *(const s8_t*)(w1tl + boff0 + k0);
    s8_t bl1 = *(const s8_t*)(w1tl + boff1 + k0);
    acc[0][0] = __builtin_amdgcn_mfma_f32_16x16x32_bf16(ah0, bh0, acc[0][0], 0, 0, 0);
    acc[0][0] = __builtin_amdgcn_mfma_f32_16x16x32_bf16(ah0, bl0, acc[0][0], 0, 0, 0);
    acc[0][0] = __builtin_amdgcn_mfma_f32_16x16x32_bf16(al0, bh0, acc[0][0], 0, 0, 0);
    acc[0][1] = __builtin_amdgcn_mfma_f32_16x16x32_bf16(ah0, bh1, acc[0][1], 0, 0, 0);
    acc[0][1] = __builtin_amdgcn_mfma_f32_16x16x32_bf16(ah0, bl1, acc[0][1], 0, 0, 0);
    acc[0][1] = __builtin_amdgcn_mfma_f32_16x16x32_bf16(al0, bh1, acc[0][1], 0, 0, 0);
    acc[1][0] = __builtin_amdgcn_mfma_f32_16x16x32_bf16(ah1, bh0, acc[1][0], 0, 0, 0);
    acc[1][0] = __builtin_amdgcn_mfma_f32_16x16x32_bf16(ah1, bl0, acc[1][0], 0, 0, 0);
    acc[1][0] = __builtin_amdgcn_mfma_f32_16x16x32_bf16(al1, bh0, acc[1][0], 0, 0, 0);
    acc[1][1] = __builtin_amdgcn_mfma_f32_16x16x32_bf16(ah1, bh1, acc[1][1], 0, 0, 0);
    acc[1][1] = __builtin_amdgcn_mfma_f32_16x16x32_bf16(ah1, bl1, acc[1][1], 0, 0, 0);
    acc[1][1] = __builtin_amdgcn_mfma_f32_16x16x32_bf16(al1, bh1, acc[1][1], 0, 0, 0);
  }

  // bias + relu + split -> Th/Tl
  {
    float b1v0 = b1[nb + l16], b1v1 = b1[nb + 16 + l16];
#pragma unroll
    for (int mi = 0; mi < 2; mi++)
#pragma unroll
      for (int ni = 0; ni < 2; ni++) {
        float bv = ni ? b1v1 : b1v0;
        int col = nb + ni * 16 + l16;
#pragma unroll
        for (int r = 0; r < 4; r++) {
          int row = mi * 16 + quad * 4 + r;
          float v = fmaxf(acc[mi][ni][r] + bv, 0.f);
          short h, l; split2(v, h, l);
          Th[row * ST + col] = h;
          Tl[row * ST + col] = l;
        }
      }
  }
  __syncthreads();

  // ---- layer 2: [32,128] @ W2[128,128] ----
  int toff0 = (0 + l16) * ST + quad * 8;
  int toff1 = (16 + l16) * ST + quad * 8;
  int coff0 = (nb + l16) * 128 + quad * 8;
  int coff1 = (nb + 16 + l16) * 128 + quad * 8;

  f4_t acc2[2][2];
#pragma unroll
  for (int mi = 0; mi < 2; mi++)
#pragma unroll
    for (int ni = 0; ni < 2; ni++) acc2[mi][ni] = (f4_t){0.f, 0.f, 0.f, 0.f};

#pragma unroll
  for (int k0 = 0; k0 < 128; k0 += 32) {
    s8_t ah0 = *(const s8_t*)&Th[toff0 + k0];
    s8_t ah1 = *(const s8_t*)&Th[toff1 + k0];
    s8_t al0 = *(const s8_t*)&Tl[toff0 + k0];
    s8_t al1 = *(const s8_t*)&Tl[toff1 + k0];
    s8_t bh0 = *(const s8_t*)(w2th + coff0 + k0);
    s8_t bh1 = *(const s8_t*)(w2th + coff1 + k0);
    s8_t bl0 = *(const s8_t*)(w2tl + coff0 + k0);
    s8_t bl1 = *(const s8_t*)(w2tl + coff1 + k0);
    acc2[0][0] = __builtin_amdgcn_mfma_f32_16x16x32_bf16(ah0, bh0, acc2[0][0], 0, 0, 0);
    acc2[0][0] = __builtin_amdgcn_mfma_f32_16x16x32_bf16(ah0, bl0, acc2[0][0], 0, 0, 0);
    acc2[0][0] = __builtin_amdgcn_mfma_f32_16x16x32_bf16(al0, bh0, acc2[0][0], 0, 0, 0);
    acc2[0][1] = __builtin_amdgcn_mfma_f32_16x16x32_bf16(ah0, bh1, acc2[0][1], 0, 0, 0);
    acc2[0][1] = __builtin_amdgcn_mfma_f32_16x16x32_bf16(ah0, bl1, acc2[0][1], 0, 0, 0);
    acc2[0][1] = __builtin_amdgcn_mfma_f32_16x16x32_bf16(al0, bh1, acc2[0][1], 0, 0, 0);
    acc2[1][0] = __builtin_amdgcn_mfma_f32_16x16x32_bf16(ah1, bh0, acc2[1][0], 0, 0, 0);
    acc2[1][0] = __builtin_amdgcn_mfma_f32_16x16x32_bf16(ah1, bl0, acc2[1][0], 0, 0, 0);
    acc2[1][0] = __builtin_amdgcn_mfma_f32_16x16x32_bf16(al1, bh0, acc2[1][0], 0, 0, 0);
    acc2[1][1] = __builtin_amdgcn_mfma_f32_16x16x32_bf16(ah1, bh1, acc2[1][1], 0, 0, 0);
    acc2[1][1] = __builtin_amdgcn_mfma_f32_16x16x32_bf16(ah1, bl1, acc2[1][1], 0, 0, 0);
    acc2[1][1] = __builtin_amdgcn_mfma_f32_16x16x32_bf16(al1, bh1, acc2[1][1], 0, 0, 0);
  }

  // bias + relu -> T2 (fp32, aliases dead Ah region; safe: post-layer1 barrier passed)
  {
    float b2v0 = b2[nb + l16], b2v1 = b2[nb + 16 + l16];
#pragma unroll
    for (int mi = 0; mi < 2; mi++)
#pragma unroll
      for (int ni = 0; ni < 2; ni++) {
        float bv = ni ? b2v1 : b2v0;
        int col = nb + ni * 16 + l16;
#pragma unroll
        for (int r = 0; r < 4; r++) {
          int row = mi * 16 + quad * 4 + r;
          T2[row * S2 + col] = fmaxf(acc2[mi][ni][r] + bv, 0.f);
        }
      }
  }
  __syncthreads();

  // ---- layer 3: out[e] = dot(t2[e], W3) + b3 ----
  int le = t >> 3, j0 = (t & 7) * 16;
  float s = 0.f;
#pragma unroll
  for (int j = 0; j < 16; j += 4) {
    float4 v = *(const float4*)(&T2[le * S2 + j0 + j]);
    float4 wv = *(const float4*)(W3 + j0 + j);
    s += v.x * wv.x + v.y * wv.y + v.z * wv.z + v.w * wv.w;
  }
  s += __shfl_down(s, 4);
  s += __shfl_down(s, 2);
  s += __shfl_down(s, 1);
  if ((t & 7) == 0) out[e0 + le] = s + b3[0];
}

// ---------------- launch ----------------

extern "C" void kernel_launch(void* const* d_in, const int* in_sizes, int n_in,
                              void* d_out, int out_size, void* d_ws, size_t ws_size,
                              hipStream_t stream) {
  const int*   node_ids = (const int*)d_in[0];
  const int*   ei       = (const int*)d_in[1];
  const int*   nei      = (const int*)d_in[2];
  const float* eattr    = (const float*)d_in[3];
  const float* emb      = (const float*)d_in[4];
  const float* W_in     = (const float*)d_in[5];
  const float* b_in     = (const float*)d_in[6];
  const float* W_out    = (const float*)d_in[7];
  const float* b_out    = (const float*)d_in[8];
  const float* W1       = (const float*)d_in[9];
  const float* b1       = (const float*)d_in[10];
  const float* W2       = (const float*)d_in[11];
  const float* b2       = (const float*)d_in[12];
  const float* W3       = (const float*)d_in[13];
  const float* b3       = (const float*)d_in[14];
  float* out = (float*)d_out;

  // workspace (floats): bufA[N*256] | bufB[N*256] | norm1[E] | norm2[E]
  //                     | dinv1[N] | dinv2[N] | bf16 weight tables (~200 KB)
  float* ws    = (float*)d_ws;
  float* bufA  = ws;
  float* bufB  = bufA + (size_t)NN * 256;
  float* norm1 = bufB + (size_t)NN * 256;
  float* norm2 = norm1 + NE;
  float* dinv1 = norm2 + NE;
  float* dinv2 = dinv1 + NN;
  short* w1th  = (short*)(dinv2 + NN);
  short* w1tl  = w1th + 32768;
  short* w2th  = w1tl + 32768;
  short* w2tl  = w2th + 16384;
  // x2 bf16 hi/lo reuse the bufA region (h2 is dead by the time k_x2cvt runs)
  short* x2h   = (short*)bufA;
  short* x2l   = x2h + (size_t)NN * 128;

  // weight split (independent, do first)
  k_wcvt<<<192, 256, 0, stream>>>(W1, W2, w1th, w1tl, w2th, w2tl);

  // degrees -> dinv -> norms
  hipMemsetAsync(dinv1, 0, 2 * (size_t)NN * sizeof(float), stream);
  k_deg<<<NE / 256, 256, 0, stream>>>(ei, nei, eattr, dinv1, dinv2);
  k_dinv<<<(2 * NN + 255) / 256, 256, 0, stream>>>(dinv1, 2 * NN);
  k_norm<<<NE / 256, 256, 0, stream>>>(ei, nei, eattr, dinv1, dinv2, norm1, norm2);

  // layer 1: h1 = emb[ids] @ W_in ; agg ; elu   (h1 in bufA, x1 in bufB)
  k_gemm_in<<<(NN + 31) / 32, 256, 0, stream>>>(emb, node_ids, W_in, bufA);
  hipMemsetAsync(bufB, 0, (size_t)NN * 256 * sizeof(float), stream);
  k_scatter1<<<NE / 8, 256, 0, stream>>>(bufA, ei, norm1, bufB);
  k_bias_elu<<<NN, 256, 0, stream>>>(bufB, b_in, 255);

  // layer 2: h2 = x1 @ W_out ; agg ; elu+split  (h2 in bufA, agg in bufB)
  k_gemm_mid<<<(NN + 31) / 32, 256, 0, stream>>>(bufB, W_out, bufA);
  float* agg2 = norm1 + 0;  // careful: need a clean N*128 fp32 buffer; norm1/2 still needed? no:
  // norm2 is still needed by scatter2 itself; norm1 is dead after scatter1.
  // But norm1 is only E floats (800k) < N*128 (6.4M). Use tail of bufB instead:
  float* aggB = bufB + (size_t)NN * 128;  // second half of bufB (x1 fully consumed by gemm_mid)
  hipMemsetAsync(aggB, 0, (size_t)NN * 128 * sizeof(float), stream);
  k_scatter2<<<NE / 16, 256, 0, stream>>>(bufA, nei, norm2, aggB);
  k_x2cvt<<<NN * 128 / 256, 256, 0, stream>>>(aggB, b_out, x2h, x2l);

  // decoder (split-bf16 MFMA)
  k_decoder<<<NE / 32, 256, 0, stream>>>(x2h, x2l, ei,
                                         w1th, w1tl, b1,
                                         w2th, w2tl, b2,
                                         W3, b3, out);
}